// Round 10
// baseline (355.758 us; speedup 1.0000x reference)
//
#include <hip/hip_runtime.h>

#define B_SZ 8
#define N_SZ 4096
#define M_SZ 2048
#define D_SZ 512

typedef __attribute__((ext_vector_type(8))) short bf16x8;
typedef __attribute__((ext_vector_type(4))) float f32x4;
typedef __attribute__((address_space(1))) const void* gptr1;
typedef __attribute__((address_space(3))) void* lptr3;

__device__ __forceinline__ unsigned short f2bf(float x) {
    unsigned int u = __builtin_bit_cast(unsigned int, x);
    u += 0x7fffu + ((u >> 16) & 1u);
    return (unsigned short)(u >> 16);
}
__device__ __forceinline__ float bf2f(unsigned short u) {
    unsigned int x = ((unsigned int)u) << 16;
    return __builtin_bit_cast(float, x);
}

__device__ __forceinline__ void vmcnt0() { asm volatile("s_waitcnt vmcnt(0)" ::: "memory"); }
__device__ __forceinline__ void vmcnt3() { asm volatile("s_waitcnt vmcnt(3)" ::: "memory"); }
__device__ __forceinline__ void vmcnt4() { asm volatile("s_waitcnt vmcnt(4)" ::: "memory"); }
__device__ __forceinline__ void vmcnt6() { asm volatile("s_waitcnt vmcnt(6)" ::: "memory"); }
// Steady certify count = loads of the halves intentionally left in flight.
// SHALLOW ring: 2 halves in flight (b.A0+b.B0): BN=256 -> 4 loads, BN=128 -> 3.
// DEEP ring: 3 halves (A0+B0+B1): BN=256 -> 6, BN=128 -> 4.
template<int BN, bool DEEP> __device__ __forceinline__ void vmcnt_steady() {
    if constexpr (DEEP) { if constexpr (BN == 256) vmcnt6(); else vmcnt4(); }
    else               { if constexpr (BN == 256) vmcnt4(); else vmcnt3(); }
}

// ---------- 8-phase 256-wide mainloop, register-cached frags, depth-templated ring ----------
// Stage one half-tile (NROWS x 64 k-elems, bf16) global -> LDS, with the k-slot
// XOR swizzle applied on the GLOBAL side (global_load_lds dest must be linear).
// LDS layout: row-major [NROWS][64] bf16 (128 B rows); 16B slot s of row r holds
// global k-slot s ^ (r & 7).
template<int NROWS>
__device__ __forceinline__ void stage_half(
    const unsigned short* __restrict__ G, int ld, int grow0, int k0,
    unsigned short* lds, int tid)
{
    const int w = tid >> 6, l = tid & 63;
#pragma unroll
    for (int c = 0; c < NROWS / 64; ++c) {
        const int idx  = (c * 8 + w) * 64 + l;      // 0 .. NROWS*8-1
        const int row  = idx >> 3;                  // local row
        const int slot = (idx & 7) ^ (row & 7);     // pre-swizzled global k-slot
        const unsigned short* ga = G + (size_t)(grow0 + row) * ld + (k0 + slot * 8);
        __builtin_amdgcn_global_load_lds((gptr1)ga, (lptr3)(lds + (c * 8 + w) * 512), 16, 0, 0);
    }
}

// Fragment reads (register-cached across phases): per K-tile window: ph_a reads
// af(QM0)+bq0, ph_b reads bq1 only, ph_c reads af(QM1) only, ph_d reads nothing.
#define PH_RA(BUF, QM)                                                                \
    _Pragma("unroll") for (int mi = 0; mi < 4; ++mi)                                  \
      _Pragma("unroll") for (int ks = 0; ks < 2; ++ks) {                              \
        const int row = (QM) * 128 + wrow + mi * 16 + lr;                             \
        af[mi][ks] = *(const bf16x8*)(As + (BUF) * ABUF + row * 64 + (((ks * 4 + kq) ^ (row & 7)) * 8)); \
      }

#define PH_RB(BUF, QN, DST)                                                           \
    _Pragma("unroll") for (int ni = 0; ni < NF2; ++ni)                                \
      _Pragma("unroll") for (int ks = 0; ks < 2; ++ks) {                              \
        const int row = (QN) * (BN / 2) + wcol + ni * 16 + lr;                        \
        DST[ni][ks] = *(const bf16x8*)(Bs + (BUF) * BBUF + row * 64 + (((ks * 4 + kq) ^ (row & 7)) * 8)); \
      }

// MFMA cluster for quadrant (QM,QN) using B-frags BQ; stage issue before the
// barrier, counted-vmcnt tail after the MFMAs. NOTE: no unparenthesized commas
// may appear inside STAGES/TAIL (macro-arg splitting — round-9 compile fail);
// depth-dependent waits go through the certify() lambda.
#define PH_MMA(QM, QN, BQ, STAGES, TAIL)                                              \
  {                                                                                   \
    STAGES;                                                                           \
    __builtin_amdgcn_s_barrier();                                                     \
    __builtin_amdgcn_s_setprio(1);                                                    \
    _Pragma("unroll") for (int mi = 0; mi < 4; ++mi)                                  \
      _Pragma("unroll") for (int ni = 0; ni < NF2; ++ni)                              \
        _Pragma("unroll") for (int ks = 0; ks < 2; ++ks)                              \
          acc[(QM) * 4 + mi][(QN) * NF2 + ni] = __builtin_amdgcn_mfma_f32_16x16x32_bf16( \
              af[mi][ks], BQ[ni][ks], acc[(QM) * 4 + mi][(QN) * NF2 + ni], 0, 0, 0);  \
    __builtin_amdgcn_s_setprio(0);                                                    \
    TAIL;                                                                             \
    __builtin_amdgcn_s_barrier();                                                     \
  }

// C[rowBase:+256, colBase:+BN] += A[256 x K] * Bt[BN x K]^T, 512 threads / 8 waves.
// Phase order per window: (QM0,QN0) -> (QM0,QN1) -> (QM1,QN1) -> (QM1,QN0).
// Ring depth is templated (measured r7/r8): SHALLOW best for short K (4 iters,
// gemm1/gemm2: fill/drain dominate), DEEP best for long K (32 iters, gemm3).
//
// SHALLOW (2 halves in flight; HW-verified r7):
//   ph1 stage b1.A1 | ph2 stage b1.B1 | ph3 b0'.A0 | ph4 b0'.B0 +vmcnt-> b1 ready
//   ph5 b0'.A1 | ph6 b0'.B1 | ph7 b1'.A0 | ph8 b1'.B0 +vmcnt-> b0' ready
//   prologue: b0 all4 + b1.{A0,B0}; certify = vmcnt(4)/vmcnt(3).
// DEEP (3 halves in flight; HW-verified r8):
//   ph1 stage b1.A1 | ph2 b0'.A0 | ph3 b0'.B0 | ph4 b0'.B1 +vmcnt-> b1 ready
//   ph5 b0'.A1 | ph6 b1'.A0 | ph7 b1'.B0 | ph8 b1'.B1 +vmcnt-> b0' ready
//   prologue: b0 all4 + b1.{A0,B0,B1}; certify = vmcnt(6)/vmcnt(4).
// Region safety for both rings verified by (region, K-tile, last-reader, stage)
// enumeration in rounds 6/7; both passed on HW.
template<int BN, bool DEEP>
__device__ __forceinline__ void mainloop8(
    const unsigned short* __restrict__ A, const unsigned short* __restrict__ Bt,
    int lda, int ldb, int rowBase, int colBase, int K,
    unsigned short* As, unsigned short* Bs, f32x4 (&acc)[8][BN / 64])
{
    constexpr int NF2  = BN / 128;      // n-frags per phase (2 or 1)
    constexpr int BNH  = BN / 2;
    constexpr int ABUF = 256 * 64, AH = 128 * 64;
    constexpr int BBUF = BN * 64,  BH = BNH * 64;
    const int tid = threadIdx.x, lane = tid & 63, w = tid >> 6;
    const int wrow = (w >> 2) * 64;
    const int wcol = (w & 3) * (BN / 8);
    const int lr = lane & 15, kq = lane >> 4;
    const int niter = K >> 7;

    auto certify = [&]() { vmcnt_steady<BN, DEEP>(); };   // comma-free wrapper for macro TAILs

    bf16x8 af[4][2], bq0[NF2][2], bq1[NF2][2];   // all indices compile-time (no scratch)

    // prologue
    stage_half<128>(A,  lda, rowBase,       0,  As,        tid);
    stage_half<BNH>(Bt, ldb, colBase,       0,  Bs,        tid);
    stage_half<128>(A,  lda, rowBase + 128, 0,  As + AH,   tid);
    stage_half<BNH>(Bt, ldb, colBase + BNH, 0,  Bs + BH,   tid);
    stage_half<128>(A,  lda, rowBase,       64, As + ABUF, tid);
    stage_half<BNH>(Bt, ldb, colBase,       64, Bs + BBUF, tid);
    if constexpr (DEEP) stage_half<BNH>(Bt, ldb, colBase + BNH, 64, Bs + BBUF + BH, tid);
    certify();
    __builtin_amdgcn_s_barrier();

    for (int I = 0; I < niter; ++I) {
        const bool nl = (I + 1 < niter);
        const int ke = I << 7;
        // ---- window0: reads buf0 (K-tile 2I) ----
        PH_RA(0, 0) PH_RB(0, 0, bq0)
        PH_MMA(0, 0, bq0, { stage_half<128>(A,  lda, rowBase + 128, ke + 64,  As + ABUF + AH, tid); }, {})  // b1.A1
        PH_RB(0, 1, bq1)
        PH_MMA(0, 1, bq1,
            { if constexpr (DEEP) { if (nl) stage_half<128>(A,  lda, rowBase,       ke + 128, As,      tid); }
              else                {          stage_half<BNH>(Bt, ldb, colBase + BNH, ke + 64,  Bs + BBUF + BH, tid); } }, {})
        PH_RA(0, 1)
        PH_MMA(1, 1, bq1,
            { if constexpr (DEEP) { if (nl) stage_half<BNH>(Bt, ldb, colBase,       ke + 128, Bs,      tid); }
              else                { if (nl) stage_half<128>(A,  lda, rowBase,       ke + 128, As,      tid); } }, {})
        PH_MMA(1, 0, bq0,
            { if constexpr (DEEP) { if (nl) stage_half<BNH>(Bt, ldb, colBase + BNH, ke + 128, Bs + BH, tid); }
              else                { if (nl) stage_half<BNH>(Bt, ldb, colBase,       ke + 128, Bs,      tid); } },
            { if (nl) certify(); else vmcnt0(); })
        // ---- window1: reads buf1 (K-tile 2I+1) ----
        PH_RA(1, 0) PH_RB(1, 0, bq0)
        PH_MMA(0, 0, bq0, { if (nl) stage_half<128>(A,  lda, rowBase + 128, ke + 128, As + AH, tid); }, {})  // b0'.A1
        PH_RB(1, 1, bq1)
        PH_MMA(0, 1, bq1,
            { if constexpr (DEEP) { if (nl) stage_half<128>(A,  lda, rowBase,       ke + 192, As + ABUF, tid); }
              else                { if (nl) stage_half<BNH>(Bt, ldb, colBase + BNH, ke + 128, Bs + BH,   tid); } }, {})
        PH_RA(1, 1)
        PH_MMA(1, 1, bq1,
            { if constexpr (DEEP) { if (nl) stage_half<BNH>(Bt, ldb, colBase,       ke + 192, Bs + BBUF, tid); }
              else                { if (nl) stage_half<128>(A,  lda, rowBase,       ke + 192, As + ABUF, tid); } }, {})
        PH_MMA(1, 0, bq0,
            { if constexpr (DEEP) { if (nl) stage_half<BNH>(Bt, ldb, colBase + BNH, ke + 192, Bs + BBUF + BH, tid); }
              else                { if (nl) stage_half<BNH>(Bt, ldb, colBase,       ke + 192, Bs + BBUF,      tid); } },
            { if (nl) certify(); })
    }
}

// ---------- prep: normalize text[1] rows -> tn, copy t1 into out, zero L & SS ----------
__global__ __launch_bounds__(256) void prep_tn_k(
    const float* __restrict__ text, unsigned short* __restrict__ tn,
    float* __restrict__ out, float* __restrict__ L, float* __restrict__ SS)
{
    const int m = blockIdx.x;
    const int t = threadIdx.x;  // 256
    const float* t1 = text + (size_t)M_SZ * D_SZ;
    float2 v = ((const float2*)(t1 + (size_t)m * D_SZ))[t];
    float s = v.x * v.x + v.y * v.y;
#pragma unroll
    for (int off = 32; off > 0; off >>= 1) s += __shfl_down(s, off);
    __shared__ float partial[4];
    if ((t & 63) == 0) partial[t >> 6] = s;
    __syncthreads();
    float norm = sqrtf(partial[0] + partial[1] + partial[2] + partial[3]);
    norm = fmaxf(norm, 1e-8f);
    const float inv = 1.f / norm;
    ushort2 pk; pk.x = f2bf(v.x * inv); pk.y = f2bf(v.y * inv);
    ((ushort2*)(tn + (size_t)m * D_SZ))[t] = pk;
#pragma unroll
    for (int b = 0; b < B_SZ; ++b)
        ((float2*)(out + ((size_t)(b * M_SZ + m)) * (2 * D_SZ) + D_SZ))[t] = v;
    if (m < 64) L[m * 256 + t] = 0.f;
    if (m < 128) SS[m * 256 + t] = 0.f;
}

// ---------- prep: transpose W (fp32 [d][e]) -> Wt (bf16 [e][d]) ----------
__global__ __launch_bounds__(256) void prep_w_k(
    const float* __restrict__ W, unsigned short* __restrict__ Wt)
{
    const int dt = blockIdx.x, et = blockIdx.y;
    const int t = threadIdx.x;
    __shared__ unsigned short tile[64][72];
    const int rr = t >> 4;
    const int cc = (t & 15) * 4;
#pragma unroll
    for (int p = 0; p < 4; ++p) {
        const int d = p * 16 + rr;
        const float4 v = *(const float4*)(W + (size_t)(dt * 64 + d) * D_SZ + et * 64 + cc);
        tile[d][cc] = f2bf(v.x); tile[d][cc + 1] = f2bf(v.y);
        tile[d][cc + 2] = f2bf(v.z); tile[d][cc + 3] = f2bf(v.w);
    }
    __syncthreads();
#pragma unroll
    for (int p = 0; p < 4; ++p) {
        const int e = p * 16 + rr;
        ushort4 pk;
        pk.x = tile[cc][e]; pk.y = tile[cc + 1][e]; pk.z = tile[cc + 2][e]; pk.w = tile[cc + 3][e];
        *(ushort4*)(Wt + (size_t)(et * 64 + e) * D_SZ + dt * 64 + cc) = pk;
    }
}

// ---------- features fp32 -> V bf16 [b*n][d] and Vt bf16 [b][d][n] ----------
__global__ __launch_bounds__(256) void convert_feat_k(
    const float* __restrict__ feat, unsigned short* __restrict__ V,
    unsigned short* __restrict__ Vt)
{
    const int nt = blockIdx.x, dt = blockIdx.y, b = blockIdx.z;
    const int t = threadIdx.x;
    __shared__ unsigned short tile[64][72];
    const int rr = t >> 4;
    const int cc = (t & 15) * 4;
#pragma unroll
    for (int p = 0; p < 4; ++p) {
        const int r = p * 16 + rr;
        const size_t grow = (size_t)(b * N_SZ + nt * 64 + r);
        const float4 v = *(const float4*)(feat + grow * D_SZ + dt * 64 + cc);
        ushort4 pk; pk.x = f2bf(v.x); pk.y = f2bf(v.y); pk.z = f2bf(v.z); pk.w = f2bf(v.w);
        *(ushort4*)(V + grow * D_SZ + dt * 64 + cc) = pk;
        tile[r][cc] = pk.x; tile[r][cc + 1] = pk.y; tile[r][cc + 2] = pk.z; tile[r][cc + 3] = pk.w;
    }
    __syncthreads();
#pragma unroll
    for (int p = 0; p < 4; ++p) {
        const int d = p * 16 + rr;
        ushort4 pk;
        pk.x = tile[cc][d]; pk.y = tile[cc + 1][d]; pk.z = tile[cc + 2][d]; pk.w = tile[cc + 3][d];
        *(ushort4*)(Vt + ((size_t)(b * D_SZ + dt * 64 + d)) * N_SZ + nt * 64 + cc) = pk;
    }
}

// ---------- gemm1 (8-phase 256x256, shallow ring): f1b = bf16(V @ Wt^T + bias); SS += sum(f1^2) ----------
__global__ __launch_bounds__(512, 1) void gemm1_k8(
    const unsigned short* __restrict__ V, const unsigned short* __restrict__ Wt,
    const float* __restrict__ bias, unsigned short* __restrict__ f1b,
    float* __restrict__ SS)
{
    __shared__ unsigned short smem[65536];   // 128 KiB staging
    unsigned short* As = smem;
    unsigned short* Bs = smem + 32768;
    f32x4 acc[8][4];
#pragma unroll
    for (int i = 0; i < 8; ++i)
#pragma unroll
        for (int j = 0; j < 4; ++j) acc[i][j] = (f32x4){0.f, 0.f, 0.f, 0.f};

    const int lin = blockIdx.x;              // 256 blocks
    const int rowBase = (lin >> 1) * 256;    // V rows (b*n)
    const int colBase = (lin & 1) * 256;     // e cols

    mainloop8<256, false>(V, Wt, D_SZ, D_SZ, rowBase, colBase, D_SZ, As, Bs, acc);

    const int tid = threadIdx.x, lane = tid & 63, w = tid >> 6;
    const int wrow = (w >> 2) * 64, wcol = (w & 3) * 32;
    const int lr = lane & 15, kq = lane >> 4;

    // bias per col-frag (invariant over a)
    float bv[4];
    int cs[4];
#pragma unroll
    for (int j = 0; j < 4; ++j) {
        cs[j] = colBase + (j >> 1) * 128 + wcol + (j & 1) * 16 + lr;
        bv[j] = bias[cs[j]];
    }
#pragma unroll
    for (int a = 0; a < 8; ++a) {
        const int r0 = rowBase + (a >> 2) * 128 + wrow + (a & 3) * 16 + kq * 4;
        float s[4] = {0.f, 0.f, 0.f, 0.f};
#pragma unroll
        for (int j = 0; j < 4; ++j) {
#pragma unroll
            for (int r = 0; r < 4; ++r) {
                const float v = acc[a][j][r] + bv[j];
                f1b[(size_t)(r0 + r) * D_SZ + cs[j]] = f2bf(v);
                s[r] += v * v;
            }
        }
#pragma unroll
        for (int off = 1; off <= 8; off <<= 1)
#pragma unroll
            for (int r = 0; r < 4; ++r) s[r] += __shfl_xor(s[r], off);
        if (lr == 0) {
#pragma unroll
            for (int r = 0; r < 4; ++r) atomicAdd(&SS[r0 + r], s[r]);
        }
    }
}

// ---------- gemm2 (8-phase 256x256, shallow ring): sim = (f1b @ tn^T) * invnorm; E = bf16(exp); L += sums ----------
__global__ __launch_bounds__(512, 1) void gemm2_k8(
    const unsigned short* __restrict__ f1b, const unsigned short* __restrict__ tn,
    const float* __restrict__ SS, unsigned short* __restrict__ E,
    float* __restrict__ L)
{
    __shared__ unsigned short smem[65536];   // 128 KiB: staging; reused as swizzled P-tile
    __shared__ float invn[256];              // per-row 1/||f1||
    unsigned short* As = smem;               // [2][256*64]
    unsigned short* Bs = smem + 32768;       // [2][256*64]
    f32x4 acc[8][4];
#pragma unroll
    for (int i = 0; i < 8; ++i)
#pragma unroll
        for (int j = 0; j < 4; ++j) acc[i][j] = (f32x4){0.f, 0.f, 0.f, 0.f};

    const int lin = blockIdx.x;              // 1024 blocks
    const int xcd = lin & 7, slot = lin >> 3;
    const int mt = slot & 7;                 // tn col-tile (inner: tn L2-resident)
    const int rt = (slot >> 3) * 8 + xcd;    // f1 row-tile pinned per XCD
    const int rowBase = rt * 256;            // f1 rows (b*4096 + n)
    const int colBase = mt * 256;            // tn rows (m)

    mainloop8<256, false>(f1b, tn, D_SZ, D_SZ, rowBase, colBase, D_SZ, As, Bs, acc);

    const int tid = threadIdx.x, lane = tid & 63, w = tid >> 6;
    if (tid < 256) {
        const float ss = SS[rowBase + tid];
        invn[tid] = 1.f / fmaxf(sqrtf(ss), 1e-8f);
    }
    __syncthreads();                         // drains DMA (last iter vmcnt(0)) + publishes invn

    const int wrow = (w >> 2) * 64, wcol = (w & 3) * 32;
    const int lr = lane & 15, kq = lane >> 4;
    const int b = rowBase >> 12;
    const int nb0 = rowBase & 4095;

    // write exp(sim*invnorm) into swizzled P[m 256][n 256] (16B slot s of row m at s^(m&7))
    unsigned short* P = smem;
    float ps[4] = {0.f, 0.f, 0.f, 0.f};
#pragma unroll
    for (int a = 0; a < 8; ++a) {
        const int n0 = (a >> 2) * 128 + wrow + (a & 3) * 16 + kq * 4;   // local n
        const float4 inr = *(const float4*)(invn + n0);
#pragma unroll
        for (int j = 0; j < 4; ++j) {
            const int m = (j >> 1) * 128 + wcol + (j & 1) * 16 + lr;    // local m
            const float e0 = __expf(acc[a][j][0] * inr.x);
            const float e1 = __expf(acc[a][j][1] * inr.y);
            const float e2 = __expf(acc[a][j][2] * inr.z);
            const float e3 = __expf(acc[a][j][3] * inr.w);
            ushort4 pk; pk.x = f2bf(e0); pk.y = f2bf(e1); pk.z = f2bf(e2); pk.w = f2bf(e3);
            *(ushort4*)(P + m * 256 + (((n0 >> 3) ^ (m & 7)) * 8) + (n0 & 7)) = pk;
            ps[j] += (e0 + e1) + (e2 + e3);
        }
    }
#pragma unroll
    for (int j = 0; j < 4; ++j) {
        float p = ps[j];
        p += __shfl_down(p, 16);
        p += __shfl_down(p, 32);
        const int m = (j >> 1) * 128 + wcol + (j & 1) * 16 + lr;
        if (lane < 16) atomicAdd(&L[b * M_SZ + colBase + m], p);
    }
    __syncthreads();

    // coalesced transposed store: 32 lanes cover 512 contiguous bytes along n
    unsigned short* Eb = E + (size_t)b * M_SZ * N_SZ;
#pragma unroll
    for (int c = 0; c < 16; ++c) {
        const int rm = c * 16 + (tid >> 5);
        const int ns = tid & 31;
        bf16x8 v = *(const bf16x8*)(P + rm * 256 + ((ns ^ (rm & 7)) * 8));
        *(bf16x8*)(Eb + (size_t)(colBase + rm) * N_SZ + nb0 + ns * 8) = v;
    }
}

// ---------- gemm3 (8-phase 256x128, deep ring): fm = (E @ Vt^T) / L -> out left half ----------
// XCD map: b = lin&7 (one batch per XCD -> Vt slice 4 MiB L2-fit; E-tiles
// streamed once, shared by the 4 concurrent dt-blocks of the same (b,mtile)).
__global__ __launch_bounds__(512, 1) void gemm3_k8(
    const unsigned short* __restrict__ E, const unsigned short* __restrict__ Vt,
    const float* __restrict__ L, float* __restrict__ out)
{
    __shared__ unsigned short smem[49152];   // 96 KiB: As 64K + Bs 32K
    unsigned short* As = smem;               // [2][256*64]
    unsigned short* Bs = smem + 32768;       // [2][128*64]
    f32x4 acc[8][2];
#pragma unroll
    for (int i = 0; i < 8; ++i)
#pragma unroll
        for (int j = 0; j < 2; ++j) acc[i][j] = (f32x4){0.f, 0.f, 0.f, 0.f};

    const int lin = blockIdx.x;              // 256 blocks
    const int b = lin & 7;                   // batch pinned per XCD
    const int mtile = (lin >> 3) & 7;        // E m-tile
    const int dt = lin >> 6;                 // Vt d-tile (0..3)
    const int rowBase = mtile * 256;         // m
    const int colBase = dt * 128;            // d

    const unsigned short* Ab = E + (size_t)b * M_SZ * N_SZ;
    const unsigned short* Bb = Vt + (size_t)b * D_SZ * N_SZ;
    mainloop8<128, true>(Ab, Bb, N_SZ, N_SZ, rowBase, colBase, N_SZ, As, Bs, acc);

    const int tid = threadIdx.x, lane = tid & 63, w = tid >> 6;
    const int wrow = (w >> 2) * 64, wcol = (w & 3) * 16;
    const int lr = lane & 15, kq = lane >> 4;

#pragma unroll
    for (int a = 0; a < 8; ++a) {
        const int r0 = rowBase + (a >> 2) * 128 + wrow + (a & 3) * 16 + kq * 4;
        float invl[4];
#pragma unroll
        for (int r = 0; r < 4; ++r) invl[r] = 1.f / L[b * M_SZ + r0 + r];
#pragma unroll
        for (int j = 0; j < 2; ++j) {
            const int d = colBase + j * 64 + wcol + lr;
#pragma unroll
            for (int r = 0; r < 4; ++r)
                out[((size_t)(b * M_SZ + r0 + r)) * (2 * D_SZ) + d] = acc[a][j][r] * invl[r];
        }
    }
}

extern "C" void kernel_launch(void* const* d_in, const int* in_sizes, int n_in,
                              void* d_out, int out_size, void* d_ws, size_t ws_size,
                              hipStream_t stream) {
    const float* features = (const float*)d_in[0];   // [8, 4096, 512]
    const float* text     = (const float*)d_in[1];   // [2, 2048, 512]
    const float* W        = (const float*)d_in[2];   // [512, 512]
    const float* bias     = (const float*)d_in[3];   // [512]
    float* out = (float*)d_out;                      // [8, 2048, 1024]
    char* ws = (char*)d_ws;

    // workspace layout (bytes)
    unsigned short* f1b = (unsigned short*)(ws + 0);            // 32 MiB (lives through gemm2)
    unsigned short* tn  = (unsigned short*)(ws + 33554432);     //  2 MiB
    unsigned short* Wt  = (unsigned short*)(ws + 35651584);     // .5 MiB
    unsigned short* V   = (unsigned short*)(ws + 36175872);     // 32 MiB
    unsigned short* Vt  = (unsigned short*)(ws + 69730304);     // 32 MiB
    float*          L   = (float*)(ws + 103284736);             // 64 KiB
    float*          SS  = (float*)(ws + 103350272);             // 128 KiB
    unsigned short* E   = (unsigned short*)(ws + 103481344);    // 128 MiB

    hipLaunchKernelGGL(prep_tn_k, dim3(M_SZ), dim3(256), 0, stream, text, tn, out, L, SS);
    hipLaunchKernelGGL(prep_w_k, dim3(8, 8), dim3(256), 0, stream, W, Wt);
    hipLaunchKernelGGL(convert_feat_k, dim3(64, 8, 8), dim3(256), 0, stream, features, V, Vt);
    hipLaunchKernelGGL(gemm1_k8, dim3(256), dim3(512), 0, stream, V, Wt, bias, f1b, SS);
    hipLaunchKernelGGL(gemm2_k8, dim3(1024), dim3(512), 0, stream, f1b, tn, SS, E, L);
    hipLaunchKernelGGL(gemm3_k8, dim3(256), dim3(512), 0, stream, E, Vt, L, out);
}

// Round 11
// 348.231 us; speedup vs baseline: 1.0216x; 1.0216x over previous
//
#include <hip/hip_runtime.h>

#define B_SZ 8
#define N_SZ 4096
#define M_SZ 2048
#define D_SZ 512

typedef __attribute__((ext_vector_type(8))) short bf16x8;
typedef __attribute__((ext_vector_type(4))) float f32x4;
typedef __attribute__((address_space(1))) const void* gptr1;
typedef __attribute__((address_space(3))) void* lptr3;

__device__ __forceinline__ unsigned short f2bf(float x) {
    unsigned int u = __builtin_bit_cast(unsigned int, x);
    u += 0x7fffu + ((u >> 16) & 1u);
    return (unsigned short)(u >> 16);
}
__device__ __forceinline__ float bf2f(unsigned short u) {
    unsigned int x = ((unsigned int)u) << 16;
    return __builtin_bit_cast(float, x);
}

__device__ __forceinline__ void vmcnt0() { asm volatile("s_waitcnt vmcnt(0)" ::: "memory"); }
__device__ __forceinline__ void vmcnt3() { asm volatile("s_waitcnt vmcnt(3)" ::: "memory"); }
__device__ __forceinline__ void vmcnt4() { asm volatile("s_waitcnt vmcnt(4)" ::: "memory"); }
__device__ __forceinline__ void vmcnt6() { asm volatile("s_waitcnt vmcnt(6)" ::: "memory"); }
// Steady certify count = loads of the halves intentionally left in flight.
// SHALLOW ring: 2 halves in flight (b.A0+b.B0): BN=256 -> 4 loads, BN=128 -> 3.
// DEEP ring: 3 halves (A0+B0+B1): BN=256 -> 6, BN=128 -> 4.
template<int BN, bool DEEP> __device__ __forceinline__ void vmcnt_steady() {
    if constexpr (DEEP) { if constexpr (BN == 256) vmcnt6(); else vmcnt4(); }
    else               { if constexpr (BN == 256) vmcnt4(); else vmcnt3(); }
}

// ---------- 8-phase 256-wide mainloop, register-cached frags, 1 barrier/phase ----------
// Stage one half-tile (NROWS x 64 k-elems, bf16) global -> LDS, with the k-slot
// XOR swizzle applied on the GLOBAL side (global_load_lds dest must be linear).
// LDS layout: row-major [NROWS][64] bf16 (128 B rows); 16B slot s of row r holds
// global k-slot s ^ (r & 7).
template<int NROWS>
__device__ __forceinline__ void stage_half(
    const unsigned short* __restrict__ G, int ld, int grow0, int k0,
    unsigned short* lds, int tid)
{
    const int w = tid >> 6, l = tid & 63;
#pragma unroll
    for (int c = 0; c < NROWS / 64; ++c) {
        const int idx  = (c * 8 + w) * 64 + l;      // 0 .. NROWS*8-1
        const int row  = idx >> 3;                  // local row
        const int slot = (idx & 7) ^ (row & 7);     // pre-swizzled global k-slot
        const unsigned short* ga = G + (size_t)(grow0 + row) * ld + (k0 + slot * 8);
        __builtin_amdgcn_global_load_lds((gptr1)ga, (lptr3)(lds + (c * 8 + w) * 512), 16, 0, 0);
    }
}

// Fragment reads (register-cached across phases): per K-tile window: ph_a reads
// af(QM0)+bq0, ph_b reads bq1 only, ph_c reads af(QM1) only, ph_d reads nothing.
#define PH_RA(BUF, QM)                                                                \
    _Pragma("unroll") for (int mi = 0; mi < 4; ++mi)                                  \
      _Pragma("unroll") for (int ks = 0; ks < 2; ++ks) {                              \
        const int row = (QM) * 128 + wrow + mi * 16 + lr;                             \
        af[mi][ks] = *(const bf16x8*)(As + (BUF) * ABUF + row * 64 + (((ks * 4 + kq) ^ (row & 7)) * 8)); \
      }

#define PH_RB(BUF, QN, DST)                                                           \
    _Pragma("unroll") for (int ni = 0; ni < NF2; ++ni)                                \
      _Pragma("unroll") for (int ks = 0; ks < 2; ++ks) {                              \
        const int row = (QN) * (BN / 2) + wcol + ni * 16 + lr;                        \
        DST[ni][ks] = *(const bf16x8*)(Bs + (BUF) * BBUF + row * 64 + (((ks * 4 + kq) ^ (row & 7)) * 8)); \
      }

// MFMA cluster for quadrant (QM,QN) using B-frags BQ; stage issue first, MFMA
// under setprio, certify in TAIL, then the SINGLE end-of-phase barrier.
// Why one barrier suffices (r11 change; re-verified by region enumeration):
//  (a) reads-before-overwrite: any stage in phase p targets a region whose last
//      LDS-read was in phase <= p-1 (tightest: ph3 stage b0'.A0, read ph1) —
//      the end-of-phase barriers of p-1.. order all waves' reads before it.
//  (b) DMA-complete-before-read: certify (own-wave vmcnt) executes BEFORE the
//      end-of-phase barrier, so when any wave passes that barrier, every wave
//      has certified; first read of the buffer is in a later phase.
//  The old pre-MFMA barrier ordered nothing (MFMA is register-only; in-phase
//  stages are disjoint from in-phase reads). NOTE: no unparenthesized commas
//  in STAGES/TAIL (macro-arg splitting); depth-waits go through certify().
#define PH_MMA(QM, QN, BQ, STAGES, TAIL)                                              \
  {                                                                                   \
    STAGES;                                                                           \
    __builtin_amdgcn_s_setprio(1);                                                    \
    _Pragma("unroll") for (int mi = 0; mi < 4; ++mi)                                  \
      _Pragma("unroll") for (int ni = 0; ni < NF2; ++ni)                              \
        _Pragma("unroll") for (int ks = 0; ks < 2; ++ks)                              \
          acc[(QM) * 4 + mi][(QN) * NF2 + ni] = __builtin_amdgcn_mfma_f32_16x16x32_bf16( \
              af[mi][ks], BQ[ni][ks], acc[(QM) * 4 + mi][(QN) * NF2 + ni], 0, 0, 0);  \
    __builtin_amdgcn_s_setprio(0);                                                    \
    TAIL;                                                                             \
    __builtin_amdgcn_s_barrier();                                                     \
  }

// C[rowBase:+256, colBase:+BN] += A[256 x K] * Bt[BN x K]^T, 512 threads / 8 waves.
// Phase order per window: (QM0,QN0) -> (QM0,QN1) -> (QM1,QN1) -> (QM1,QN0).
// Ring depth templated (measured r7/r8): SHALLOW best for short K (gemm1/gemm2),
// DEEP best for long K (gemm3).
//
// SHALLOW (2 halves in flight; HW-verified r7):
//   ph1 stage b1.A1 | ph2 stage b1.B1 | ph3 b0'.A0 | ph4 b0'.B0 +vmcnt-> b1 ready
//   ph5 b0'.A1 | ph6 b0'.B1 | ph7 b1'.A0 | ph8 b1'.B0 +vmcnt-> b0' ready
//   prologue: b0 all4 + b1.{A0,B0}; certify = vmcnt(4)/vmcnt(3).
// DEEP (3 halves in flight; HW-verified r8):
//   ph1 stage b1.A1 | ph2 b0'.A0 | ph3 b0'.B0 | ph4 b0'.B1 +vmcnt-> b1 ready
//   ph5 b0'.A1 | ph6 b1'.A0 | ph7 b1'.B0 | ph8 b1'.B1 +vmcnt-> b0' ready
//   prologue: b0 all4 + b1.{A0,B0,B1}; certify = vmcnt(6)/vmcnt(4).
template<int BN, bool DEEP>
__device__ __forceinline__ void mainloop8(
    const unsigned short* __restrict__ A, const unsigned short* __restrict__ Bt,
    int lda, int ldb, int rowBase, int colBase, int K,
    unsigned short* As, unsigned short* Bs, f32x4 (&acc)[8][BN / 64])
{
    constexpr int NF2  = BN / 128;      // n-frags per phase (2 or 1)
    constexpr int BNH  = BN / 2;
    constexpr int ABUF = 256 * 64, AH = 128 * 64;
    constexpr int BBUF = BN * 64,  BH = BNH * 64;
    const int tid = threadIdx.x, lane = tid & 63, w = tid >> 6;
    const int wrow = (w >> 2) * 64;
    const int wcol = (w & 3) * (BN / 8);
    const int lr = lane & 15, kq = lane >> 4;
    const int niter = K >> 7;

    auto certify = [&]() { vmcnt_steady<BN, DEEP>(); };   // comma-free wrapper for macro TAILs

    bf16x8 af[4][2], bq0[NF2][2], bq1[NF2][2];   // all indices compile-time (no scratch)

    // prologue
    stage_half<128>(A,  lda, rowBase,       0,  As,        tid);
    stage_half<BNH>(Bt, ldb, colBase,       0,  Bs,        tid);
    stage_half<128>(A,  lda, rowBase + 128, 0,  As + AH,   tid);
    stage_half<BNH>(Bt, ldb, colBase + BNH, 0,  Bs + BH,   tid);
    stage_half<128>(A,  lda, rowBase,       64, As + ABUF, tid);
    stage_half<BNH>(Bt, ldb, colBase,       64, Bs + BBUF, tid);
    if constexpr (DEEP) stage_half<BNH>(Bt, ldb, colBase + BNH, 64, Bs + BBUF + BH, tid);
    certify();
    __builtin_amdgcn_s_barrier();

    for (int I = 0; I < niter; ++I) {
        const bool nl = (I + 1 < niter);
        const int ke = I << 7;
        // ---- window0: reads buf0 (K-tile 2I) ----
        PH_RA(0, 0) PH_RB(0, 0, bq0)
        PH_MMA(0, 0, bq0, { stage_half<128>(A,  lda, rowBase + 128, ke + 64,  As + ABUF + AH, tid); }, {})  // b1.A1
        PH_RB(0, 1, bq1)
        PH_MMA(0, 1, bq1,
            { if constexpr (DEEP) { if (nl) stage_half<128>(A,  lda, rowBase,       ke + 128, As,      tid); }
              else                {          stage_half<BNH>(Bt, ldb, colBase + BNH, ke + 64,  Bs + BBUF + BH, tid); } }, {})
        PH_RA(0, 1)
        PH_MMA(1, 1, bq1,
            { if constexpr (DEEP) { if (nl) stage_half<BNH>(Bt, ldb, colBase,       ke + 128, Bs,      tid); }
              else                { if (nl) stage_half<128>(A,  lda, rowBase,       ke + 128, As,      tid); } }, {})
        PH_MMA(1, 0, bq0,
            { if constexpr (DEEP) { if (nl) stage_half<BNH>(Bt, ldb, colBase + BNH, ke + 128, Bs + BH, tid); }
              else                { if (nl) stage_half<BNH>(Bt, ldb, colBase,       ke + 128, Bs,      tid); } },
            { if (nl) certify(); else vmcnt0(); })
        // ---- window1: reads buf1 (K-tile 2I+1) ----
        PH_RA(1, 0) PH_RB(1, 0, bq0)
        PH_MMA(0, 0, bq0, { if (nl) stage_half<128>(A,  lda, rowBase + 128, ke + 128, As + AH, tid); }, {})  // b0'.A1
        PH_RB(1, 1, bq1)
        PH_MMA(0, 1, bq1,
            { if constexpr (DEEP) { if (nl) stage_half<128>(A,  lda, rowBase,       ke + 192, As + ABUF, tid); }
              else                { if (nl) stage_half<BNH>(Bt, ldb, colBase + BNH, ke + 128, Bs + BH,   tid); } }, {})
        PH_RA(1, 1)
        PH_MMA(1, 1, bq1,
            { if constexpr (DEEP) { if (nl) stage_half<BNH>(Bt, ldb, colBase,       ke + 192, Bs + BBUF, tid); }
              else                { if (nl) stage_half<128>(A,  lda, rowBase,       ke + 192, As + ABUF, tid); } }, {})
        PH_MMA(1, 0, bq0,
            { if constexpr (DEEP) { if (nl) stage_half<BNH>(Bt, ldb, colBase + BNH, ke + 192, Bs + BBUF + BH, tid); }
              else                { if (nl) stage_half<BNH>(Bt, ldb, colBase,       ke + 192, Bs + BBUF,      tid); } },
            { if (nl) certify(); })
    }
}

// ---------- prep: normalize text[1] rows -> tn, copy t1 into out, zero L & SS ----------
__global__ __launch_bounds__(256) void prep_tn_k(
    const float* __restrict__ text, unsigned short* __restrict__ tn,
    float* __restrict__ out, float* __restrict__ L, float* __restrict__ SS)
{
    const int m = blockIdx.x;
    const int t = threadIdx.x;  // 256
    const float* t1 = text + (size_t)M_SZ * D_SZ;
    float2 v = ((const float2*)(t1 + (size_t)m * D_SZ))[t];
    float s = v.x * v.x + v.y * v.y;
#pragma unroll
    for (int off = 32; off > 0; off >>= 1) s += __shfl_down(s, off);
    __shared__ float partial[4];
    if ((t & 63) == 0) partial[t >> 6] = s;
    __syncthreads();
    float norm = sqrtf(partial[0] + partial[1] + partial[2] + partial[3]);
    norm = fmaxf(norm, 1e-8f);
    const float inv = 1.f / norm;
    ushort2 pk; pk.x = f2bf(v.x * inv); pk.y = f2bf(v.y * inv);
    ((ushort2*)(tn + (size_t)m * D_SZ))[t] = pk;
#pragma unroll
    for (int b = 0; b < B_SZ; ++b)
        ((float2*)(out + ((size_t)(b * M_SZ + m)) * (2 * D_SZ) + D_SZ))[t] = v;
    if (m < 64) L[m * 256 + t] = 0.f;
    if (m < 128) SS[m * 256 + t] = 0.f;
}

// ---------- prep: transpose W (fp32 [d][e]) -> Wt (bf16 [e][d]) ----------
__global__ __launch_bounds__(256) void prep_w_k(
    const float* __restrict__ W, unsigned short* __restrict__ Wt)
{
    const int dt = blockIdx.x, et = blockIdx.y;
    const int t = threadIdx.x;
    __shared__ unsigned short tile[64][72];
    const int rr = t >> 4;
    const int cc = (t & 15) * 4;
#pragma unroll
    for (int p = 0; p < 4; ++p) {
        const int d = p * 16 + rr;
        const float4 v = *(const float4*)(W + (size_t)(dt * 64 + d) * D_SZ + et * 64 + cc);
        tile[d][cc] = f2bf(v.x); tile[d][cc + 1] = f2bf(v.y);
        tile[d][cc + 2] = f2bf(v.z); tile[d][cc + 3] = f2bf(v.w);
    }
    __syncthreads();
#pragma unroll
    for (int p = 0; p < 4; ++p) {
        const int e = p * 16 + rr;
        ushort4 pk;
        pk.x = tile[cc][e]; pk.y = tile[cc + 1][e]; pk.z = tile[cc + 2][e]; pk.w = tile[cc + 3][e];
        *(ushort4*)(Wt + (size_t)(et * 64 + e) * D_SZ + dt * 64 + cc) = pk;
    }
}

// ---------- features fp32 -> V bf16 [b*n][d] and Vt bf16 [b][d][n] ----------
__global__ __launch_bounds__(256) void convert_feat_k(
    const float* __restrict__ feat, unsigned short* __restrict__ V,
    unsigned short* __restrict__ Vt)
{
    const int nt = blockIdx.x, dt = blockIdx.y, b = blockIdx.z;
    const int t = threadIdx.x;
    __shared__ unsigned short tile[64][72];
    const int rr = t >> 4;
    const int cc = (t & 15) * 4;
#pragma unroll
    for (int p = 0; p < 4; ++p) {
        const int r = p * 16 + rr;
        const size_t grow = (size_t)(b * N_SZ + nt * 64 + r);
        const float4 v = *(const float4*)(feat + grow * D_SZ + dt * 64 + cc);
        ushort4 pk; pk.x = f2bf(v.x); pk.y = f2bf(v.y); pk.z = f2bf(v.z); pk.w = f2bf(v.w);
        *(ushort4*)(V + grow * D_SZ + dt * 64 + cc) = pk;
        tile[r][cc] = pk.x; tile[r][cc + 1] = pk.y; tile[r][cc + 2] = pk.z; tile[r][cc + 3] = pk.w;
    }
    __syncthreads();
#pragma unroll
    for (int p = 0; p < 4; ++p) {
        const int d = p * 16 + rr;
        ushort4 pk;
        pk.x = tile[cc][d]; pk.y = tile[cc + 1][d]; pk.z = tile[cc + 2][d]; pk.w = tile[cc + 3][d];
        *(ushort4*)(Vt + ((size_t)(b * D_SZ + dt * 64 + d)) * N_SZ + nt * 64 + cc) = pk;
    }
}

// ---------- gemm1 (8-phase 256x256, shallow ring): f1b = bf16(V @ Wt^T + bias); SS += sum(f1^2) ----------
__global__ __launch_bounds__(512, 1) void gemm1_k8(
    const unsigned short* __restrict__ V, const unsigned short* __restrict__ Wt,
    const float* __restrict__ bias, unsigned short* __restrict__ f1b,
    float* __restrict__ SS)
{
    __shared__ unsigned short smem[65536];   // 128 KiB staging
    unsigned short* As = smem;
    unsigned short* Bs = smem + 32768;
    f32x4 acc[8][4];
#pragma unroll
    for (int i = 0; i < 8; ++i)
#pragma unroll
        for (int j = 0; j < 4; ++j) acc[i][j] = (f32x4){0.f, 0.f, 0.f, 0.f};

    const int lin = blockIdx.x;              // 256 blocks
    const int rowBase = (lin >> 1) * 256;    // V rows (b*n)
    const int colBase = (lin & 1) * 256;     // e cols

    mainloop8<256, false>(V, Wt, D_SZ, D_SZ, rowBase, colBase, D_SZ, As, Bs, acc);

    const int tid = threadIdx.x, lane = tid & 63, w = tid >> 6;
    const int wrow = (w >> 2) * 64, wcol = (w & 3) * 32;
    const int lr = lane & 15, kq = lane >> 4;

    // bias per col-frag (invariant over a)
    float bv[4];
    int cs[4];
#pragma unroll
    for (int j = 0; j < 4; ++j) {
        cs[j] = colBase + (j >> 1) * 128 + wcol + (j & 1) * 16 + lr;
        bv[j] = bias[cs[j]];
    }
#pragma unroll
    for (int a = 0; a < 8; ++a) {
        const int r0 = rowBase + (a >> 2) * 128 + wrow + (a & 3) * 16 + kq * 4;
        float s[4] = {0.f, 0.f, 0.f, 0.f};
#pragma unroll
        for (int j = 0; j < 4; ++j) {
#pragma unroll
            for (int r = 0; r < 4; ++r) {
                const float v = acc[a][j][r] + bv[j];
                f1b[(size_t)(r0 + r) * D_SZ + cs[j]] = f2bf(v);
                s[r] += v * v;
            }
        }
#pragma unroll
        for (int off = 1; off <= 8; off <<= 1)
#pragma unroll
            for (int r = 0; r < 4; ++r) s[r] += __shfl_xor(s[r], off);
        if (lr == 0) {
#pragma unroll
            for (int r = 0; r < 4; ++r) atomicAdd(&SS[r0 + r], s[r]);
        }
    }
}

// ---------- gemm2 (8-phase 256x256, shallow ring): sim = (f1b @ tn^T) * invnorm; E = bf16(exp); L += sums ----------
__global__ __launch_bounds__(512, 1) void gemm2_k8(
    const unsigned short* __restrict__ f1b, const unsigned short* __restrict__ tn,
    const float* __restrict__ SS, unsigned short* __restrict__ E,
    float* __restrict__ L)
{
    __shared__ unsigned short smem[65536];   // 128 KiB: staging; reused as swizzled P-tile
    __shared__ float invn[256];              // per-row 1/||f1||
    unsigned short* As = smem;               // [2][256*64]
    unsigned short* Bs = smem + 32768;       // [2][256*64]
    f32x4 acc[8][4];
#pragma unroll
    for (int i = 0; i < 8; ++i)
#pragma unroll
        for (int j = 0; j < 4; ++j) acc[i][j] = (f32x4){0.f, 0.f, 0.f, 0.f};

    const int lin = blockIdx.x;              // 1024 blocks
    const int xcd = lin & 7, slot = lin >> 3;
    const int mt = slot & 7;                 // tn col-tile (inner: tn L2-resident)
    const int rt = (slot >> 3) * 8 + xcd;    // f1 row-tile pinned per XCD
    const int rowBase = rt * 256;            // f1 rows (b*4096 + n)
    const int colBase = mt * 256;            // tn rows (m)

    mainloop8<256, false>(f1b, tn, D_SZ, D_SZ, rowBase, colBase, D_SZ, As, Bs, acc);

    const int tid = threadIdx.x, lane = tid & 63, w = tid >> 6;
    if (tid < 256) {
        const float ss = SS[rowBase + tid];
        invn[tid] = 1.f / fmaxf(sqrtf(ss), 1e-8f);
    }
    __syncthreads();                         // drains DMA (last iter vmcnt(0)) + publishes invn

    const int wrow = (w >> 2) * 64, wcol = (w & 3) * 32;
    const int lr = lane & 15, kq = lane >> 4;
    const int b = rowBase >> 12;
    const int nb0 = rowBase & 4095;

    // write exp(sim*invnorm) into swizzled P[m 256][n 256] (16B slot s of row m at s^(m&7))
    unsigned short* P = smem;
    float ps[4] = {0.f, 0.f, 0.f, 0.f};
#pragma unroll
    for (int a = 0; a < 8; ++a) {
        const int n0 = (a >> 2) * 128 + wrow + (a & 3) * 16 + kq * 4;   // local n
        const float4 inr = *(const float4*)(invn + n0);
#pragma unroll
        for (int j = 0; j < 4; ++j) {
            const int m = (j >> 1) * 128 + wcol + (j & 1) * 16 + lr;    // local m
            const float e0 = __expf(acc[a][j][0] * inr.x);
            const float e1 = __expf(acc[a][j][1] * inr.y);
            const float e2 = __expf(acc[a][j][2] * inr.z);
            const float e3 = __expf(acc[a][j][3] * inr.w);
            ushort4 pk; pk.x = f2bf(e0); pk.y = f2bf(e1); pk.z = f2bf(e2); pk.w = f2bf(e3);
            *(ushort4*)(P + m * 256 + (((n0 >> 3) ^ (m & 7)) * 8) + (n0 & 7)) = pk;
            ps[j] += (e0 + e1) + (e2 + e3);
        }
    }
#pragma unroll
    for (int j = 0; j < 4; ++j) {
        float p = ps[j];
        p += __shfl_down(p, 16);
        p += __shfl_down(p, 32);
        const int m = (j >> 1) * 128 + wcol + (j & 1) * 16 + lr;
        if (lane < 16) atomicAdd(&L[b * M_SZ + colBase + m], p);
    }
    __syncthreads();

    // coalesced transposed store: 32 lanes cover 512 contiguous bytes along n
    unsigned short* Eb = E + (size_t)b * M_SZ * N_SZ;
#pragma unroll
    for (int c = 0; c < 16; ++c) {
        const int rm = c * 16 + (tid >> 5);
        const int ns = tid & 31;
        bf16x8 v = *(const bf16x8*)(P + rm * 256 + ((ns ^ (rm & 7)) * 8));
        *(bf16x8*)(Eb + (size_t)(colBase + rm) * N_SZ + nb0 + ns * 8) = v;
    }
}

// ---------- gemm3 (8-phase 256x128, deep ring): fm = (E @ Vt^T) / L -> out left half ----------
// XCD map: b = lin&7 (one batch per XCD -> Vt slice 4 MiB L2-fit; E-tiles
// streamed once, shared by the 4 concurrent dt-blocks of the same (b,mtile)).
__global__ __launch_bounds__(512, 1) void gemm3_k8(
    const unsigned short* __restrict__ E, const unsigned short* __restrict__ Vt,
    const float* __restrict__ L, float* __restrict__ out)
{
    __shared__ unsigned short smem[49152];   // 96 KiB: As 64K + Bs 32K
    unsigned short* As = smem;               // [2][256*64]
    unsigned short* Bs = smem + 32768;       // [2][128*64]
    f32x4 acc[8][2];
#pragma unroll
    for (int i = 0; i < 8; ++i)
#pragma unroll
        for (int j = 0; j < 2; ++j) acc[i][j] = (f32x4){0.f, 0.f, 0.f, 0.f};

    const int lin = blockIdx.x;              // 256 blocks
    const int b = lin & 7;                   // batch pinned per XCD
    const int mtile = (lin >> 3) & 7;        // E m-tile
    const int dt = lin >> 6;                 // Vt d-tile (0..3)
    const int rowBase = mtile * 256;         // m
    const int colBase = dt * 128;            // d

    const unsigned short* Ab = E + (size_t)b * M_SZ * N_SZ;
    const unsigned short* Bb = Vt + (size_t)b * D_SZ * N_SZ;
    mainloop8<128, true>(Ab, Bb, N_SZ, N_SZ, rowBase, colBase, N_SZ, As, Bs, acc);

    const int tid = threadIdx.x, lane = tid & 63, w = tid >> 6;
    const int wrow = (w >> 2) * 64, wcol = (w & 3) * 16;
    const int lr = lane & 15, kq = lane >> 4;

#pragma unroll
    for (int a = 0; a < 8; ++a) {
        const int r0 = rowBase + (a >> 2) * 128 + wrow + (a & 3) * 16 + kq * 4;
        float invl[4];
#pragma unroll
        for (int r = 0; r < 4; ++r) invl[r] = 1.f / L[b * M_SZ + r0 + r];
#pragma unroll
        for (int j = 0; j < 2; ++j) {
            const int d = colBase + j * 64 + wcol + lr;
#pragma unroll
            for (int r = 0; r < 4; ++r)
                out[((size_t)(b * M_SZ + r0 + r)) * (2 * D_SZ) + d] = acc[a][j][r] * invl[r];
        }
    }
}

extern "C" void kernel_launch(void* const* d_in, const int* in_sizes, int n_in,
                              void* d_out, int out_size, void* d_ws, size_t ws_size,
                              hipStream_t stream) {
    const float* features = (const float*)d_in[0];   // [8, 4096, 512]
    const float* text     = (const float*)d_in[1];   // [2, 2048, 512]
    const float* W        = (const float*)d_in[2];   // [512, 512]
    const float* bias     = (const float*)d_in[3];   // [512]
    float* out = (float*)d_out;                      // [8, 2048, 1024]
    char* ws = (char*)d_ws;

    // workspace layout (bytes)
    unsigned short* f1b = (unsigned short*)(ws + 0);            // 32 MiB (lives through gemm2)
    unsigned short* tn  = (unsigned short*)(ws + 33554432);     //  2 MiB
    unsigned short* Wt  = (unsigned short*)(ws + 35651584);     // .5 MiB
    unsigned short* V   = (unsigned short*)(ws + 36175872);     // 32 MiB
    unsigned short* Vt  = (unsigned short*)(ws + 69730304);     // 32 MiB
    float*          L   = (float*)(ws + 103284736);             // 64 KiB
    float*          SS  = (float*)(ws + 103350272);             // 128 KiB
    unsigned short* E   = (unsigned short*)(ws + 103481344);    // 128 MiB

    hipLaunchKernelGGL(prep_tn_k, dim3(M_SZ), dim3(256), 0, stream, text, tn, out, L, SS);
    hipLaunchKernelGGL(prep_w_k, dim3(8, 8), dim3(256), 0, stream, W, Wt);
    hipLaunchKernelGGL(convert_feat_k, dim3(64, 8, 8), dim3(256), 0, stream, features, V, Vt);
    hipLaunchKernelGGL(gemm1_k8, dim3(256), dim3(512), 0, stream, V, Wt, bias, f1b, SS);
    hipLaunchKernelGGL(gemm2_k8, dim3(1024), dim3(512), 0, stream, f1b, tn, SS, E, L);
    hipLaunchKernelGGL(gemm3_k8, dim3(256), dim3(512), 0, stream, E, Vt, L, out);
}